// Round 6
// baseline (1007.311 us; speedup 1.0000x reference)
//
#include <hip/hip_runtime.h>

#define Bdim   4096
#define INdim  4096
#define OUTdim 2048
#define Knz    32

typedef float  f4  __attribute__((ext_vector_type(4)));
typedef short  s4  __attribute__((ext_vector_type(4)));

// f32 -> bf16 round-to-nearest-even
__device__ inline unsigned short f2bf(float f) {
  unsigned u = __float_as_uint(f);
  u += 0x7fffu + ((u >> 16) & 1u);
  return (unsigned short)(u >> 16);
}

// Kernel 1: xT[i][b] = bf16(x[b][i]).  64x64 tiles via LDS.  96 MB stream at
// HBM floor (~15us).  nt on both sides: keep the stream out of L2.
__global__ __launch_bounds__(256) void k_transpose(const float* __restrict__ x,
                                                   unsigned short* __restrict__ xT) {
  __shared__ float tile[64][65];
  const int bi = blockIdx.x;      // 64-row tile (b dim)
  const int ii = blockIdx.y;      // 64-col tile (IN dim)
  const int t = threadIdx.x;
  const int r = t >> 4;           // 0..15
  const int c = t & 15;           // 0..15
#pragma unroll
  for (int rr = 0; rr < 64; rr += 16) {
    const f4 v = __builtin_nontemporal_load(reinterpret_cast<const f4*>(
        &x[(size_t)(bi * 64 + rr + r) * INdim + ii * 64 + c * 4]));
    tile[rr + r][c * 4 + 0] = v.x;
    tile[rr + r][c * 4 + 1] = v.y;
    tile[rr + r][c * 4 + 2] = v.z;
    tile[rr + r][c * 4 + 3] = v.w;
  }
  __syncthreads();
#pragma unroll
  for (int rr = 0; rr < 64; rr += 16) {
    const int il = rr + r;
    s4 o;
    o.x = (short)f2bf(tile[c * 4 + 0][il]);
    o.y = (short)f2bf(tile[c * 4 + 1][il]);
    o.z = (short)f2bf(tile[c * 4 + 2][il]);
    o.w = (short)f2bf(tile[c * 4 + 3][il]);
    __builtin_nontemporal_store(o, reinterpret_cast<s4*>(
        &xT[(size_t)(ii * 64 + il) * Bdim + bi * 64 + c * 4]));
  }
}

// Kernel 2: gather-dot.
// Geometry (PROVEN in R5: FETCH 20.6MB, WRITE 32.7MB — keep exactly):
//   2048 blocks; xcd = wg&7, opp = wg>>3; bt = xcd*2 + (opp>>7) (2MB phased
//   slices per XCD L2); op = opp&127; wave w -> 4 o; lane -> 4 b (uint2).
// Occupancy (R5's failure): unconstrained scheduler hoisted to VGPR=256 ->
//   2 waves/SIMD, 11% occ, latency-bound. Fix: launch_bounds(256,4) caps at
//   128 VGPR (4 waves/SIMD) and the k-loop is batched 16 loads at a time
//   (32 load VGPRs + 16 acc + addr ~= 70 live) so no spill even at the cap.
//   R4 showed waves_per_eu=8 -> spill disaster; 4 is the sweet spot.
__global__ __launch_bounds__(256, 4) void k_gather(const unsigned short* __restrict__ xT,
                                                   const int* __restrict__ cols,
                                                   const float* __restrict__ values,
                                                   float* __restrict__ out) {
  const int wg = blockIdx.x;                 // 0..2047
  const int xcd = wg & 7;
  const int opp = wg >> 3;                   // 0..255 per XCD
  const int bt = xcd * 2 + (opp >> 7);       // 16 b-tiles of 256
  const int op = opp & 127;                  // 128 o-panels of 16
  const int w = threadIdx.x >> 6;            // wave 0..3 -> o sub-panel
  const int l = threadIdx.x & 63;            // lane -> 4 consecutive b
  const int b0 = bt * 256 + l * 4;
  const int o0 = op * 16 + w * 4;

  float acc[4][4];                           // [oc][b-sub], static idx -> regs
#pragma unroll
  for (int i = 0; i < 4; ++i)
#pragma unroll
    for (int j = 0; j < 4; ++j) acc[i][j] = 0.f;

  const unsigned short* __restrict__ xb = xT + b0;

#pragma unroll
  for (int oc = 0; oc < 4; ++oc) {
    const int o = o0 + oc;
    const int* __restrict__ cp = cols + o * Knz;
    const float* __restrict__ vp = values + o * Knz;
#pragma unroll
    for (int k0 = 0; k0 < Knz; k0 += 16) {
      // Batch: 16 independent gathers in flight (static-indexed array ->
      // registers), then 16 unpack+FMA groups.
      uint2 u[16];
#pragma unroll
      for (int k = 0; k < 16; ++k) {
        const int col = cp[k0 + k];          // wave-uniform -> s_load
        u[k] = *reinterpret_cast<const uint2*>(&xb[(size_t)col * Bdim]);
      }
#pragma unroll
      for (int k = 0; k < 16; ++k) {
        const float val = vp[k0 + k];        // wave-uniform -> s_load
        acc[oc][0] = fmaf(__uint_as_float(u[k].x << 16),         val, acc[oc][0]);
        acc[oc][1] = fmaf(__uint_as_float(u[k].x & 0xffff0000u), val, acc[oc][1]);
        acc[oc][2] = fmaf(__uint_as_float(u[k].y << 16),         val, acc[oc][2]);
        acc[oc][3] = fmaf(__uint_as_float(u[k].y & 0xffff0000u), val, acc[oc][3]);
      }
    }
  }

  // 4 rows x 16B cached stores; 64B line completed by this block's 4 waves.
#pragma unroll
  for (int r = 0; r < 4; ++r) {
    *reinterpret_cast<f4*>(&out[(size_t)(b0 + r) * OUTdim + o0]) =
        (f4){acc[0][r], acc[1][r], acc[2][r], acc[3][r]};
  }
}

// Correct-but-slow fallback if ws can't hold xT (32 MB).
__global__ __launch_bounds__(256) void k_naive(const float* __restrict__ x,
                                               const float* __restrict__ values,
                                               const int* __restrict__ cols,
                                               float* __restrict__ out) {
  const size_t id = (size_t)blockIdx.x * 256 + threadIdx.x;
  const int o = (int)(id % OUTdim);
  const int b = (int)(id / OUTdim);
  float a = 0.f;
  for (int k = 0; k < Knz; ++k) {
    const int col = cols[o * Knz + k];
    a = fmaf(x[(size_t)b * INdim + col], values[o * Knz + k], a);
  }
  out[id] = a;
}

extern "C" void kernel_launch(void* const* d_in, const int* in_sizes, int n_in,
                              void* d_out, int out_size, void* d_ws, size_t ws_size,
                              hipStream_t stream) {
  const float* x = (const float*)d_in[0];
  const float* values = (const float*)d_in[1];
  const int* cols = (const int*)d_in[2];
  float* out = (float*)d_out;

  const size_t need = (size_t)INdim * Bdim * sizeof(unsigned short);  // 32 MB
  if (ws_size >= need) {
    unsigned short* xT = (unsigned short*)d_ws;
    k_transpose<<<dim3(64, 64), 256, 0, stream>>>(x, xT);
    k_gather<<<2048, 256, 0, stream>>>(xT, cols, values, out);
  } else {
    k_naive<<<(Bdim * (size_t)OUTdim) / 256, 256, 0, stream>>>(x, values, cols, out);
  }
}

// Round 7
// 112.394 us; speedup vs baseline: 8.9623x; 8.9623x over previous
//
#include <hip/hip_runtime.h>

#define Bdim   4096
#define INdim  4096
#define OUTdim 2048
#define Knz    32

typedef float  f4  __attribute__((ext_vector_type(4)));
typedef short  s4  __attribute__((ext_vector_type(4)));

// f32 -> bf16 round-to-nearest-even
__device__ inline unsigned short f2bf(float f) {
  unsigned u = __float_as_uint(f);
  u += 0x7fffu + ((u >> 16) & 1u);
  return (unsigned short)(u >> 16);
}

// Kernel 1: xT[i][b] = bf16(x[b][i]).  64x64 tiles via LDS.  96 MB stream at
// HBM floor (~15us).  nt on both sides: keep the stream out of L2.
__global__ __launch_bounds__(256) void k_transpose(const float* __restrict__ x,
                                                   unsigned short* __restrict__ xT) {
  __shared__ float tile[64][65];
  const int bi = blockIdx.x;      // 64-row tile (b dim)
  const int ii = blockIdx.y;      // 64-col tile (IN dim)
  const int t = threadIdx.x;
  const int r = t >> 4;           // 0..15
  const int c = t & 15;           // 0..15
#pragma unroll
  for (int rr = 0; rr < 64; rr += 16) {
    const f4 v = __builtin_nontemporal_load(reinterpret_cast<const f4*>(
        &x[(size_t)(bi * 64 + rr + r) * INdim + ii * 64 + c * 4]));
    tile[rr + r][c * 4 + 0] = v.x;
    tile[rr + r][c * 4 + 1] = v.y;
    tile[rr + r][c * 4 + 2] = v.z;
    tile[rr + r][c * 4 + 3] = v.w;
  }
  __syncthreads();
#pragma unroll
  for (int rr = 0; rr < 64; rr += 16) {
    const int il = rr + r;
    s4 o;
    o.x = (short)f2bf(tile[c * 4 + 0][il]);
    o.y = (short)f2bf(tile[c * 4 + 1][il]);
    o.z = (short)f2bf(tile[c * 4 + 2][il]);
    o.w = (short)f2bf(tile[c * 4 + 3][il]);
    __builtin_nontemporal_store(o, reinterpret_cast<s4*>(
        &xT[(size_t)(ii * 64 + il) * Bdim + bi * 64 + c * 4]));
  }
}

// Kernel 2: gather-dot.
// Geometry (PROVEN R5: FETCH 20.6MB, WRITE 32.7MB — unchanged):
//   2048 blocks; xcd=wg&7; bt = xcd*2+(opp>>7) (phased 2MB slices per XCD L2);
//   op = opp&127; wave w -> 4 o; lane -> 4 consecutive b (uint2 gathers,
//   wave-uniform col/val -> scalar loads / SGPR address arithmetic).
// Schedule (R5 failed: unconstrained hoist -> VGPR 256, 2 waves/SIMD;
//   R4/R6 failed: launch_bounds waves-arg halves the budget -> spill):
//   hand-rotated 2-deep pipeline — batch j+1 (8 loads, 16 VGPRs) issues while
//   batch j's FMAs execute; sched_barrier(0) at each iteration boundary stops
//   deeper hoisting. Live set ~70 regs; NO waves-per-eu arg anywhere.
__global__ __launch_bounds__(256) void k_gather(const unsigned short* __restrict__ xT,
                                                const int* __restrict__ cols,
                                                const float* __restrict__ values,
                                                float* __restrict__ out) {
  const int wg = blockIdx.x;                 // 0..2047
  const int xcd = wg & 7;
  const int opp = wg >> 3;                   // 0..255 per XCD
  const int bt = xcd * 2 + (opp >> 7);       // 16 b-tiles of 256
  const int op = opp & 127;                  // 128 o-panels of 16
  const int w = threadIdx.x >> 6;            // wave 0..3 -> o sub-panel
  const int l = threadIdx.x & 63;            // lane -> 4 consecutive b
  const int b0 = bt * 256 + l * 4;
  const int o0 = op * 16 + w * 4;

  float acc[4][4];                           // [oc][b-sub], static idx -> regs
#pragma unroll
  for (int i = 0; i < 4; ++i)
#pragma unroll
    for (int j = 0; j < 4; ++j) acc[i][j] = 0.f;

  const unsigned short* __restrict__ xb = xT + b0;
  const int* __restrict__ cp = cols + o0 * Knz;     // rows oc=0..3 contiguous
  const float* __restrict__ vp = values + o0 * Knz;

  uint2 u[2][8];                             // 2-deep rotating load window

  // Prologue: batch 0 in flight.
#pragma unroll
  for (int k = 0; k < 8; ++k)
    u[0][k] = *reinterpret_cast<const uint2*>(&xb[(size_t)cp[k] * Bdim]);

  // 16 batches: j -> oc = j>>2, k0 = (j&3)*8.  All indices compile-time
  // after unroll (rule #20: no runtime-indexed arrays).
#pragma unroll
  for (int j = 0; j < 16; ++j) {
    const int oc = j >> 2;
    const int k0 = (j & 3) * 8;
    if (j < 15) {
      const int jn = j + 1;
      const int kn = (jn >> 2) * Knz + (jn & 3) * 8;
#pragma unroll
      for (int k = 0; k < 8; ++k)
        u[jn & 1][k] = *reinterpret_cast<const uint2*>(&xb[(size_t)cp[kn + k] * Bdim]);
    }
#pragma unroll
    for (int k = 0; k < 8; ++k) {
      const float val = vp[oc * Knz + k0 + k];       // wave-uniform -> s_load
      const uint2 g = u[j & 1][k];
      acc[oc][0] = fmaf(__uint_as_float(g.x << 16),         val, acc[oc][0]);
      acc[oc][1] = fmaf(__uint_as_float(g.x & 0xffff0000u), val, acc[oc][1]);
      acc[oc][2] = fmaf(__uint_as_float(g.y << 16),         val, acc[oc][2]);
      acc[oc][3] = fmaf(__uint_as_float(g.y & 0xffff0000u), val, acc[oc][3]);
    }
    __builtin_amdgcn_sched_barrier(0);       // bound live window to 2 batches
  }

  // 4 rows x 16B cached stores; 64B line completed by this block's 4 waves.
#pragma unroll
  for (int r = 0; r < 4; ++r) {
    *reinterpret_cast<f4*>(&out[(size_t)(b0 + r) * OUTdim + o0]) =
        (f4){acc[0][r], acc[1][r], acc[2][r], acc[3][r]};
  }
}

// Correct-but-slow fallback if ws can't hold xT (32 MB).
__global__ __launch_bounds__(256) void k_naive(const float* __restrict__ x,
                                               const float* __restrict__ values,
                                               const int* __restrict__ cols,
                                               float* __restrict__ out) {
  const size_t id = (size_t)blockIdx.x * 256 + threadIdx.x;
  const int o = (int)(id % OUTdim);
  const int b = (int)(id / OUTdim);
  float a = 0.f;
  for (int k = 0; k < Knz; ++k) {
    const int col = cols[o * Knz + k];
    a = fmaf(x[(size_t)b * INdim + col], values[o * Knz + k], a);
  }
  out[id] = a;
}

extern "C" void kernel_launch(void* const* d_in, const int* in_sizes, int n_in,
                              void* d_out, int out_size, void* d_ws, size_t ws_size,
                              hipStream_t stream) {
  const float* x = (const float*)d_in[0];
  const float* values = (const float*)d_in[1];
  const int* cols = (const int*)d_in[2];
  float* out = (float*)d_out;

  const size_t need = (size_t)INdim * Bdim * sizeof(unsigned short);  // 32 MB
  if (ws_size >= need) {
    unsigned short* xT = (unsigned short*)d_ws;
    k_transpose<<<dim3(64, 64), 256, 0, stream>>>(x, xT);
    k_gather<<<2048, 256, 0, stream>>>(xT, cols, values, out);
  } else {
    k_naive<<<(Bdim * (size_t)OUTdim) / 256, 256, 0, stream>>>(x, values, cols, out);
  }
}

// Round 8
// 80.637 us; speedup vs baseline: 12.4919x; 1.3938x over previous
//
#include <hip/hip_runtime.h>

#define Bdim   4096
#define INdim  4096
#define OUTdim 2048
#define Knz    32

typedef float  f4  __attribute__((ext_vector_type(4)));
typedef short  s4  __attribute__((ext_vector_type(4)));

// f32 -> bf16 round-to-nearest-even
__device__ inline unsigned short f2bf(float f) {
  unsigned u = __float_as_uint(f);
  u += 0x7fffu + ((u >> 16) & 1u);
  return (unsigned short)(u >> 16);
}

// Kernel 1: xT[i][b] = bf16(x[b][i]).  64x64 tiles via LDS.  96 MB stream at
// HBM floor (~15-19us).  nt on both sides: keep the stream out of L2.
__global__ __launch_bounds__(256) void k_transpose(const float* __restrict__ x,
                                                   unsigned short* __restrict__ xT) {
  __shared__ float tile[64][65];
  const int bi = blockIdx.x;      // 64-row tile (b dim)
  const int ii = blockIdx.y;      // 64-col tile (IN dim)
  const int t = threadIdx.x;
  const int r = t >> 4;           // 0..15
  const int c = t & 15;           // 0..15
#pragma unroll
  for (int rr = 0; rr < 64; rr += 16) {
    const f4 v = __builtin_nontemporal_load(reinterpret_cast<const f4*>(
        &x[(size_t)(bi * 64 + rr + r) * INdim + ii * 64 + c * 4]));
    tile[rr + r][c * 4 + 0] = v.x;
    tile[rr + r][c * 4 + 1] = v.y;
    tile[rr + r][c * 4 + 2] = v.z;
    tile[rr + r][c * 4 + 3] = v.w;
  }
  __syncthreads();
#pragma unroll
  for (int rr = 0; rr < 64; rr += 16) {
    const int il = rr + r;
    s4 o;
    o.x = (short)f2bf(tile[c * 4 + 0][il]);
    o.y = (short)f2bf(tile[c * 4 + 1][il]);
    o.z = (short)f2bf(tile[c * 4 + 2][il]);
    o.w = (short)f2bf(tile[c * 4 + 3][il]);
    __builtin_nontemporal_store(o, reinterpret_cast<s4*>(
        &xT[(size_t)(ii * 64 + il) * Bdim + bi * 64 + c * 4]));
  }
}

// Kernel 2: gather-dot.
// Geometry (PROVEN R5/R7: FETCH 20.6MB, WRITE 32.7MB — unchanged):
//   2048 blocks; xcd=wg&7; bt=xcd*2+(opp>>7) (phased 2MB slices per XCD L2);
//   op=opp&127; wave w -> 4 o; lane -> 4 consecutive b.
// Addressing (R7's failure: per-lane col loads + VALU addr chains hoisted to
//   VGPR 248 -> 2 waves/SIMD, latency-bound):
//   cols/values preloaded into 2+2 VGPRs per wave; per-gather col/val via
//   __builtin_amdgcn_readlane (compile-time lane) -> provably UNIFORM ->
//   address folds to SGPR-pair SALU; gather = global_load_dwordx2 saddr form
//   with one shared lane-offset VGPR. Per-gather VGPR cost = 2 (dest only);
//   SGPR bases are consumed at issue. Spill structurally impossible.
// Pipeline: 4-deep batch window (u[4][8] = 64 dest regs) -> >=32KB in flight
//   per SIMD even at 2 waves/SIMD; compiler emits counted vmcnt for reg dests.
__global__ __launch_bounds__(256) void k_gather(const unsigned short* __restrict__ xT,
                                                const int* __restrict__ cols,
                                                const float* __restrict__ values,
                                                float* __restrict__ out) {
  const int wg = blockIdx.x;                 // 0..2047
  const int xcd = wg & 7;
  const int opp = wg >> 3;                   // 0..255 per XCD
  const int bt = xcd * 2 + (opp >> 7);       // 16 b-tiles of 256
  const int op = opp & 127;                  // 128 o-panels of 16
  const int w = threadIdx.x >> 6;            // wave 0..3 -> o sub-panel
  const int l = threadIdx.x & 63;            // lane -> 4 consecutive b
  const int b0 = bt * 256 + l * 4;
  const int o0 = op * 16 + w * 4;

  // Preload this wave's 128 cols / 128 values into 2+2 VGPRs (coalesced).
  const int* __restrict__ cw = cols + o0 * Knz;
  const float* __restrict__ vw = values + o0 * Knz;
  const int c0i = cw[l];
  const int c1i = cw[64 + l];
  const int v0i = __float_as_int(vw[l]);
  const int v1i = __float_as_int(vw[64 + l]);

  const unsigned short* __restrict__ xtb = xT + bt * 256;  // wave-uniform base
  const int le = l * 4;                                    // lane elem offset

  float acc[4][4];                           // [oc][b-sub], static idx -> regs
#pragma unroll
  for (int i = 0; i < 4; ++i)
#pragma unroll
    for (int j = 0; j < 4; ++j) acc[i][j] = 0.f;

  uint2 u[4][8];                             // 4-deep rotating load window

  // Prologue: batches 0..2 in flight (24 loads).
#pragma unroll
  for (int j = 0; j < 3; ++j)
#pragma unroll
    for (int k = 0; k < 8; ++k) {
      const int g = j * 8 + k;               // compile-time after unroll
      const int col = (g < 64) ? __builtin_amdgcn_readlane(c0i, g)
                               : __builtin_amdgcn_readlane(c1i, g - 64);
      u[j][k] = *reinterpret_cast<const uint2*>(xtb + (size_t)col * Bdim + le);
    }

  // 16 batches: batch j consumed while j+1..j+3 are in flight.
#pragma unroll
  for (int j = 0; j < 16; ++j) {
    if (j < 13) {
      const int jn = j + 3;
#pragma unroll
      for (int k = 0; k < 8; ++k) {
        const int g = jn * 8 + k;
        const int col = (g < 64) ? __builtin_amdgcn_readlane(c0i, g)
                                 : __builtin_amdgcn_readlane(c1i, g - 64);
        u[jn & 3][k] = *reinterpret_cast<const uint2*>(xtb + (size_t)col * Bdim + le);
      }
    }
    const int oc = j >> 2;
#pragma unroll
    for (int k = 0; k < 8; ++k) {
      const int g = j * 8 + k;
      const float val = __int_as_float((g < 64) ? __builtin_amdgcn_readlane(v0i, g)
                                                : __builtin_amdgcn_readlane(v1i, g - 64));
      const uint2 gu = u[j & 3][k];
      acc[oc][0] = fmaf(__uint_as_float(gu.x << 16),         val, acc[oc][0]);
      acc[oc][1] = fmaf(__uint_as_float(gu.x & 0xffff0000u), val, acc[oc][1]);
      acc[oc][2] = fmaf(__uint_as_float(gu.y << 16),         val, acc[oc][2]);
      acc[oc][3] = fmaf(__uint_as_float(gu.y & 0xffff0000u), val, acc[oc][3]);
    }
    __builtin_amdgcn_sched_barrier(0);
  }

  // 4 rows x 16B cached stores; 64B line completed by this block's 4 waves.
#pragma unroll
  for (int r = 0; r < 4; ++r) {
    *reinterpret_cast<f4*>(&out[(size_t)(b0 + r) * OUTdim + o0]) =
        (f4){acc[0][r], acc[1][r], acc[2][r], acc[3][r]};
  }
}

// Correct-but-slow fallback if ws can't hold xT (32 MB).
__global__ __launch_bounds__(256) void k_naive(const float* __restrict__ x,
                                               const float* __restrict__ values,
                                               const int* __restrict__ cols,
                                               float* __restrict__ out) {
  const size_t id = (size_t)blockIdx.x * 256 + threadIdx.x;
  const int o = (int)(id % OUTdim);
  const int b = (int)(id / OUTdim);
  float a = 0.f;
  for (int k = 0; k < Knz; ++k) {
    const int col = cols[o * Knz + k];
    a = fmaf(x[(size_t)b * INdim + col], values[o * Knz + k], a);
  }
  out[id] = a;
}

extern "C" void kernel_launch(void* const* d_in, const int* in_sizes, int n_in,
                              void* d_out, int out_size, void* d_ws, size_t ws_size,
                              hipStream_t stream) {
  const float* x = (const float*)d_in[0];
  const float* values = (const float*)d_in[1];
  const int* cols = (const int*)d_in[2];
  float* out = (float*)d_out;

  const size_t need = (size_t)INdim * Bdim * sizeof(unsigned short);  // 32 MB
  if (ws_size >= need) {
    unsigned short* xT = (unsigned short*)d_ws;
    k_transpose<<<dim3(64, 64), 256, 0, stream>>>(x, xT);
    k_gather<<<2048, 256, 0, stream>>>(xT, cols, values, out);
  } else {
    k_naive<<<(Bdim * (size_t)OUTdim) / 256, 256, 0, stream>>>(x, values, cols, out);
  }
}